// Round 1
// baseline (125.718 us; speedup 1.0000x reference)
//
#include <hip/hip_runtime.h>

typedef __attribute__((ext_vector_type(8))) _Float16 half8;
typedef __attribute__((ext_vector_type(4))) _Float16 half4;
typedef __attribute__((ext_vector_type(4))) float f32x4;

#define ALPHA 0.2f

// ---------------- K0a: W fp32 -> fp16 ----------------
__global__ __launch_bounds__(256) void k_convW(const float* __restrict__ W,
                                               _Float16* __restrict__ W16) {
  int i = (blockIdx.x * 256 + threadIdx.x) * 4;
  float4 v = *reinterpret_cast<const float4*>(W + i);
  half4 hv = {(_Float16)v.x, (_Float16)v.y, (_Float16)v.z, (_Float16)v.w};
  *reinterpret_cast<half4*>(W16 + i) = hv;
}

// ---------------- K0b: u1 = W^T a1, u2 = W^T a2 ----------------
__global__ __launch_bounds__(256) void k_uvec(const float* __restrict__ W,
                                              const float* __restrict__ a1,
                                              const float* __restrict__ a2,
                                              float* __restrict__ u1,
                                              float* __restrict__ u2) {
  int k = blockIdx.x * 256 + threadIdx.x;  // 0..511
  float x1 = 0.f, x2 = 0.f;
  for (int o = 0; o < 256; ++o) {
    float wv = W[o * 512 + k];
    x1 += wv * a1[o];
    x2 += wv * a2[o];
  }
  u1[k] = x1;
  u2[k] = x2;
}

// ---------------- K1: s1,s2 = h . u (one wave per row) ----------------
__global__ __launch_bounds__(256) void k_scores(const float* __restrict__ h,
                                                const float* __restrict__ u1,
                                                const float* __restrict__ u2,
                                                float* __restrict__ s1,
                                                float* __restrict__ s2) {
  int t = threadIdx.x;
  int lane = t & 63;
  int w = t >> 6;
  int row = blockIdx.x * 4 + w;  // 0..16383
  const float* hr = h + (size_t)row * 512;
  float x1 = 0.f, x2 = 0.f;
#pragma unroll
  for (int p = 0; p < 2; ++p) {
    int c = p * 256 + lane * 4;
    float4 hv = *reinterpret_cast<const float4*>(hr + c);
    float4 v1 = *reinterpret_cast<const float4*>(u1 + c);
    float4 v2 = *reinterpret_cast<const float4*>(u2 + c);
    x1 += hv.x * v1.x + hv.y * v1.y + hv.z * v1.z + hv.w * v1.w;
    x2 += hv.x * v2.x + hv.y * v2.y + hv.z * v2.z + hv.w * v2.w;
  }
#pragma unroll
  for (int off = 32; off >= 1; off >>= 1) {
    x1 += __shfl_xor(x1, off);
    x2 += __shfl_xor(x2, off);
  }
  if (lane == 0) {
    s1[row] = x1;
    s2[row] = x2;
  }
}

// ---------------- K1b: per-batch max of s2 ----------------
__global__ __launch_bounds__(256) void k_smax(const float* __restrict__ s2,
                                              float* __restrict__ smax) {
  __shared__ float red[4];
  int b = blockIdx.x, t = threadIdx.x;
  float m = -1e30f;
  for (int j = t; j < 2048; j += 256) m = fmaxf(m, s2[b * 2048 + j]);
#pragma unroll
  for (int off = 32; off >= 1; off >>= 1) m = fmaxf(m, __shfl_xor(m, off));
  if ((t & 63) == 0) red[t >> 6] = m;
  __syncthreads();
  if (t == 0) smax[b] = fmaxf(fmaxf(red[0], red[1]), fmaxf(red[2], red[3]));
}

// ---------------- K2: Wh GEMM (fp16 MFMA), writes WhT[b][c][n] fp16 ----------------
// block: 64 rows x 256 cols, 4 waves (each 64x64), K-loop over 512 in steps of 64
__global__ __launch_bounds__(256) void k_gemm_wh(const float* __restrict__ h,
                                                 const _Float16* __restrict__ W16,
                                                 _Float16* __restrict__ WhT) {
  __shared__ _Float16 A_lds[64][72];   // +8 pad: 2-way-max bank aliasing
  __shared__ _Float16 B_lds[256][72];
  int t = threadIdx.x;
  int lane = t & 63;
  int w = t >> 6;
  int i0 = blockIdx.x * 64;  // global row in [0,16384)
  int b = i0 >> 11;
  int n0 = i0 & 2047;
  const f32x4 fzero = {0.f, 0.f, 0.f, 0.f};
  f32x4 acc[4][4];
#pragma unroll
  for (int mi = 0; mi < 4; ++mi)
#pragma unroll
    for (int ni = 0; ni < 4; ++ni) acc[mi][ni] = fzero;

  for (int k0 = 0; k0 < 512; k0 += 64) {
    // stage A: h[i0..i0+64][k0..k0+64] fp32 -> fp16
#pragma unroll
    for (int p = 0; p < 4; ++p) {
      int r = (t >> 4) + p * 16;
      int c = (t & 15) * 4;
      float4 v = *reinterpret_cast<const float4*>(h + (size_t)(i0 + r) * 512 + k0 + c);
      half4 hv = {(_Float16)v.x, (_Float16)v.y, (_Float16)v.z, (_Float16)v.w};
      *reinterpret_cast<half4*>(&A_lds[r][c]) = hv;
    }
    // stage B: W16[n][k0..k0+64] (row-major over n => k-contiguous per n)
#pragma unroll
    for (int p = 0; p < 8; ++p) {
      int n = (t >> 3) + p * 32;
      int c = (t & 7) * 8;
      half8 v = *reinterpret_cast<const half8*>(W16 + n * 512 + k0 + c);
      *reinterpret_cast<half8*>(&B_lds[n][c]) = v;
    }
    __syncthreads();
#pragma unroll
    for (int kk = 0; kk < 2; ++kk) {
      int ka = (lane >> 4) * 8 + kk * 32;
      half8 afr[4], bfr[4];
#pragma unroll
      for (int mi = 0; mi < 4; ++mi)
        afr[mi] = *reinterpret_cast<half8*>(&A_lds[(lane & 15) + 16 * mi][ka]);
#pragma unroll
      for (int ni = 0; ni < 4; ++ni)
        bfr[ni] = *reinterpret_cast<half8*>(&B_lds[(lane & 15) + 16 * ni + 64 * w][ka]);
#pragma unroll
      for (int mi = 0; mi < 4; ++mi)
#pragma unroll
        for (int ni = 0; ni < 4; ++ni)
          acc[mi][ni] = __builtin_amdgcn_mfma_f32_16x16x32_f16(afr[mi], bfr[ni], acc[mi][ni], 0, 0, 0);
    }
    __syncthreads();
  }
  // epilogue: write transposed WhT[b][c][n0+r], 4 consecutive n per lane (8B store)
#pragma unroll
  for (int mi = 0; mi < 4; ++mi)
#pragma unroll
    for (int ni = 0; ni < 4; ++ni) {
      int r = 16 * mi + (lane >> 4) * 4;
      int c = 64 * w + 16 * ni + (lane & 15);
      f32x4 a = acc[mi][ni];
      half4 hv = {(_Float16)a[0], (_Float16)a[1], (_Float16)a[2], (_Float16)a[3]};
      *reinterpret_cast<half4*>(WhT + ((size_t)b * 256 + c) * 2048 + n0 + r) = hv;
    }
}

// ---------------- K3: fused softmax(P) @ Wh + ELU ----------------
// grid: 256 blocks, blockIdx&7 = batch (XCD-grouped), (blockIdx>>3)*64 = row block
__global__ __launch_bounds__(256) void k_attn(const _Float16* __restrict__ WhT,
                                              const float* __restrict__ s1,
                                              const float* __restrict__ s2,
                                              const float* __restrict__ smax,
                                              float* __restrict__ out) {
  __shared__ _Float16 P_lds[64][72];
  __shared__ float d_lds[64];
  int t = threadIdx.x;
  int lane = t & 63;
  int w = t >> 6;
  int b = blockIdx.x & 7;
  int i0 = (blockIdx.x >> 3) * 64;
  const float* s1b = s1 + b * 2048;
  const float* s2b = s2 + b * 2048;
  const _Float16* whtb = WhT + (size_t)b * 256 * 2048;
  int ri = t >> 2;         // row 0..63 this thread builds P for
  int cj = (t & 3) * 16;   // 16-col chunk
  float s1v = s1b[i0 + ri];
  float mrow = s1v + smax[b];
  mrow = mrow > 0.f ? mrow : ALPHA * mrow;  // closed-form row max (LR monotonic)
  float dsum = 0.f;
  const f32x4 fzero = {0.f, 0.f, 0.f, 0.f};
  f32x4 acc[4][4];
#pragma unroll
  for (int mi = 0; mi < 4; ++mi)
#pragma unroll
    for (int ni = 0; ni < 4; ++ni) acc[mi][ni] = fzero;

  for (int j0 = 0; j0 < 2048; j0 += 64) {
    // build P tile in fp16 (the MFMA A operand, shared by all 4 waves)
    float pv[16];
#pragma unroll
    for (int q = 0; q < 4; ++q) {
      float4 sv = *reinterpret_cast<const float4*>(s2b + j0 + cj + q * 4);
      float e;
      e = s1v + sv.x; e = e > 0.f ? e : ALPHA * e; pv[q * 4 + 0] = __expf(e - mrow);
      e = s1v + sv.y; e = e > 0.f ? e : ALPHA * e; pv[q * 4 + 1] = __expf(e - mrow);
      e = s1v + sv.z; e = e > 0.f ? e : ALPHA * e; pv[q * 4 + 2] = __expf(e - mrow);
      e = s1v + sv.w; e = e > 0.f ? e : ALPHA * e; pv[q * 4 + 3] = __expf(e - mrow);
    }
    half8 ph0, ph1;
#pragma unroll
    for (int x = 0; x < 8; ++x) {
      ph0[x] = (_Float16)pv[x];
      ph1[x] = (_Float16)pv[8 + x];
    }
    // denominator from the fp16-rounded values (consistent with numerator)
#pragma unroll
    for (int x = 0; x < 8; ++x) dsum += (float)ph0[x] + (float)ph1[x];
    *reinterpret_cast<half8*>(&P_lds[ri][cj]) = ph0;
    *reinterpret_cast<half8*>(&P_lds[ri][cj + 8]) = ph1;
    __syncthreads();
#pragma unroll
    for (int kk = 0; kk < 2; ++kk) {
      int ka = (lane >> 4) * 8 + kk * 32;  // local j
      half8 afr[4];
#pragma unroll
      for (int mi = 0; mi < 4; ++mi)
        afr[mi] = *reinterpret_cast<half8*>(&P_lds[(lane & 15) + 16 * mi][ka]);
#pragma unroll
      for (int ni = 0; ni < 4; ++ni) {
        int c = 64 * w + 16 * ni + (lane & 15);
        half8 bfr = *reinterpret_cast<const half8*>(whtb + (size_t)c * 2048 + j0 + ka);
#pragma unroll
        for (int mi = 0; mi < 4; ++mi)
          acc[mi][ni] = __builtin_amdgcn_mfma_f32_16x16x32_f16(afr[mi], bfr, acc[mi][ni], 0, 0, 0);
      }
    }
    __syncthreads();
  }
  // reduce denominator across the 4 threads sharing each row
  dsum += __shfl_xor(dsum, 1);
  dsum += __shfl_xor(dsum, 2);
  if ((t & 3) == 0) d_lds[ri] = dsum;
  __syncthreads();
  // epilogue: divide, ELU, store fp32
#pragma unroll
  for (int mi = 0; mi < 4; ++mi) {
#pragma unroll
    for (int ni = 0; ni < 4; ++ni) {
      int c = 64 * w + 16 * ni + (lane & 15);
      int rb = 16 * mi + (lane >> 4) * 4;
#pragma unroll
      for (int reg = 0; reg < 4; ++reg) {
        int r = rb + reg;
        float v = acc[mi][ni][reg] / d_lds[r];
        v = v > 0.f ? v : (__expf(v) - 1.f);
        out[((size_t)b * 2048 + i0 + r) * 256 + c] = v;
      }
    }
  }
}

extern "C" void kernel_launch(void* const* d_in, const int* in_sizes, int n_in,
                              void* d_out, int out_size, void* d_ws, size_t ws_size,
                              hipStream_t stream) {
  (void)in_sizes; (void)n_in; (void)out_size; (void)ws_size;
  const float* h = (const float*)d_in[0];
  const float* W = (const float*)d_in[1];
  const float* a1 = (const float*)d_in[2];
  const float* a2 = (const float*)d_in[3];
  float* out = (float*)d_out;
  char* ws = (char*)d_ws;
  // workspace layout (bytes)
  _Float16* WhT = (_Float16*)(ws);                 // 8*256*2048*2 = 8388608
  _Float16* W16 = (_Float16*)(ws + 8388608);       // 256*512*2    = 262144
  float* u1 = (float*)(ws + 8650752);              // 512*4
  float* u2 = (float*)(ws + 8652800);              // 512*4
  float* s1 = (float*)(ws + 8654848);              // 16384*4
  float* s2 = (float*)(ws + 8720384);              // 16384*4
  float* smax = (float*)(ws + 8785920);            // 8*4

  hipLaunchKernelGGL(k_convW, dim3(128), dim3(256), 0, stream, W, W16);
  hipLaunchKernelGGL(k_uvec, dim3(2), dim3(256), 0, stream, W, a1, a2, u1, u2);
  hipLaunchKernelGGL(k_scores, dim3(4096), dim3(256), 0, stream, h, u1, u2, s1, s2);
  hipLaunchKernelGGL(k_smax, dim3(8), dim3(256), 0, stream, s2, smax);
  hipLaunchKernelGGL(k_gemm_wh, dim3(256), dim3(256), 0, stream, h, W16, WhT);
  hipLaunchKernelGGL(k_attn, dim3(256), dim3(256), 0, stream, WhT, s1, s2, smax, out);
}

// Round 2
// 75.566 us; speedup vs baseline: 1.6637x; 1.6637x over previous
//
#include <hip/hip_runtime.h>

typedef __attribute__((ext_vector_type(8))) _Float16 half8;
typedef __attribute__((ext_vector_type(4))) _Float16 half4;
typedef __attribute__((ext_vector_type(4))) float f32x4;

#define ALPHA 0.2f

__device__ __forceinline__ void gload_lds16(const void* g, void* l) {
  __builtin_amdgcn_global_load_lds((const __attribute__((address_space(1))) unsigned int*)g,
                                   (__attribute__((address_space(3))) unsigned int*)l, 16, 0, 0);
}

// ---------------- K0a: W fp32 -> fp16, PRE-SWIZZLED (unit8 XOR (n&7)) ----------------
__global__ __launch_bounds__(256) void k_convW(const float* __restrict__ W,
                                               _Float16* __restrict__ W16) {
  int idx4 = blockIdx.x * 256 + threadIdx.x;  // half4 unit
  int n = idx4 >> 7;                          // row 0..255
  int q = idx4 & 127;                         // half4 within row
  float4 v = *reinterpret_cast<const float4*>(W + n * 512 + q * 4);
  half4 hv = {(_Float16)v.x, (_Float16)v.y, (_Float16)v.z, (_Float16)v.w};
  int kp = (q * 4) ^ ((n & 7) << 3);          // swizzle within 64-elem blocks
  *reinterpret_cast<half4*>(W16 + n * 512 + kp) = hv;
}

// ---------------- K0b: u = W^T a  (one block per k) ----------------
__global__ __launch_bounds__(256) void k_uvec(const float* __restrict__ W,
                                              const float* __restrict__ a1,
                                              const float* __restrict__ a2,
                                              float* __restrict__ u1,
                                              float* __restrict__ u2) {
  __shared__ float r1[4], r2[4];
  int k = blockIdx.x, t = threadIdx.x;
  float wv = W[t * 512 + k];
  float x1 = wv * a1[t];
  float x2 = wv * a2[t];
#pragma unroll
  for (int off = 32; off >= 1; off >>= 1) {
    x1 += __shfl_xor(x1, off);
    x2 += __shfl_xor(x2, off);
  }
  if ((t & 63) == 0) { r1[t >> 6] = x1; r2[t >> 6] = x2; }
  __syncthreads();
  if (t == 0) {
    u1[k] = r1[0] + r1[1] + r1[2] + r1[3];
    u2[k] = r2[0] + r2[1] + r2[2] + r2[3];
  }
}

// ---------------- K1b: per-batch max of s2 ----------------
__global__ __launch_bounds__(256) void k_smax(const float* __restrict__ s2,
                                              float* __restrict__ smax) {
  __shared__ float red[4];
  int b = blockIdx.x, t = threadIdx.x;
  float m = -1e30f;
  for (int j = t; j < 2048; j += 256) m = fmaxf(m, s2[b * 2048 + j]);
#pragma unroll
  for (int off = 32; off >= 1; off >>= 1) m = fmaxf(m, __shfl_xor(m, off));
  if ((t & 63) == 0) red[t >> 6] = m;
  __syncthreads();
  if (t == 0) smax[b] = fmaxf(fmaxf(red[0], red[1]), fmaxf(red[2], red[3]));
}

// ---------------- K2: Wh GEMM + fused s1/s2, writes SWIZZLED WhT[b][c][n] ----------------
// block: 32 rows x 256 cols, 4 waves (each 32x64), 512 blocks (2/CU)
__global__ __launch_bounds__(256) void k_gemm_wh(const float* __restrict__ h,
                                                 const _Float16* __restrict__ W16,
                                                 const float* __restrict__ u1,
                                                 const float* __restrict__ u2,
                                                 float* __restrict__ s1o,
                                                 float* __restrict__ s2o,
                                                 _Float16* __restrict__ WhT) {
  __shared__ _Float16 Ab[2][32 * 64];    // 4 KB each, swizzled (reg-staged)
  __shared__ _Float16 Bb[2][256 * 64];   // 32 KB each, linear copy of pre-swizzled W16
  const int t = threadIdx.x, lane = t & 63, w = t >> 6;
  const int i0 = blockIdx.x * 32;        // global row 0..16383
  const int b = i0 >> 11, n0 = i0 & 2047;
  const int ar = t >> 3, au = t & 7;     // A-stage: row 0..31, 8-float chunk 0..7
  const float* hrow = h + (size_t)(i0 + ar) * 512 + au * 8;

  f32x4 acc[2][4];
#pragma unroll
  for (int mi = 0; mi < 2; ++mi)
#pragma unroll
    for (int ni = 0; ni < 4; ++ni) acc[mi][ni] = (f32x4){0.f, 0.f, 0.f, 0.f};

  // prologue: load A(0) regs, stage B(0) via global_load_lds
  float4 aR0 = *reinterpret_cast<const float4*>(hrow);
  float4 aR1 = *reinterpret_cast<const float4*>(hrow + 4);
#pragma unroll
  for (int q = 0; q < 8; ++q) {
    int idx = (q * 4 + w) * 64 + lane;
    int nn = idx >> 3, uu = idx & 7;
    gload_lds16(W16 + nn * 512 + uu * 8, (char*)&Bb[0][0] + idx * 16);
  }
  float x1 = 0.f, x2 = 0.f;

  for (int kt = 0; kt < 8; ++kt) {
    const int cur = kt & 1;
    // ds_write A(kt) (+ fused s1/s2 partials on the same registers)
    {
      half8 av;
      av[0] = (_Float16)aR0.x; av[1] = (_Float16)aR0.y;
      av[2] = (_Float16)aR0.z; av[3] = (_Float16)aR0.w;
      av[4] = (_Float16)aR1.x; av[5] = (_Float16)aR1.y;
      av[6] = (_Float16)aR1.z; av[7] = (_Float16)aR1.w;
      *reinterpret_cast<half8*>((char*)&Ab[cur][0] + ar * 128 + ((au * 16) ^ ((ar & 7) << 4))) = av;
      const float* up1 = u1 + kt * 64 + au * 8;
      const float* up2 = u2 + kt * 64 + au * 8;
      float4 u1a = *reinterpret_cast<const float4*>(up1);
      float4 u1b = *reinterpret_cast<const float4*>(up1 + 4);
      float4 u2a = *reinterpret_cast<const float4*>(up2);
      float4 u2b = *reinterpret_cast<const float4*>(up2 + 4);
      x1 += aR0.x * u1a.x + aR0.y * u1a.y + aR0.z * u1a.z + aR0.w * u1a.w
          + aR1.x * u1b.x + aR1.y * u1b.y + aR1.z * u1b.z + aR1.w * u1b.w;
      x2 += aR0.x * u2a.x + aR0.y * u2a.y + aR0.z * u2a.z + aR0.w * u2a.w
          + aR1.x * u2b.x + aR1.y * u2b.y + aR1.z * u2b.z + aR1.w * u2b.w;
    }
    __syncthreads();  // A(kt) visible; B(kt) loads drained
    if (kt < 7) {     // prefetch tile kt+1 (lands during compute below)
      const int k0 = (kt + 1) * 64;
      aR0 = *reinterpret_cast<const float4*>(hrow + k0);
      aR1 = *reinterpret_cast<const float4*>(hrow + k0 + 4);
#pragma unroll
      for (int q = 0; q < 8; ++q) {
        int idx = (q * 4 + w) * 64 + lane;
        int nn = idx >> 3, uu = idx & 7;
        gload_lds16(W16 + nn * 512 + k0 + uu * 8, (char*)&Bb[cur ^ 1][0] + idx * 16);
      }
    }
    // compute tile kt
    const char* Ac = (const char*)&Ab[cur][0];
    const char* Bc = (const char*)&Bb[cur][0];
#pragma unroll
    for (int kk = 0; kk < 2; ++kk) {
      const int jb = (lane >> 4) * 16 + kk * 64;
      half8 afr[2];
#pragma unroll
      for (int mi = 0; mi < 2; ++mi) {
        int rr = (lane & 15) + 16 * mi;
        afr[mi] = *reinterpret_cast<const half8*>(Ac + rr * 128 + (jb ^ ((rr & 7) << 4)));
      }
#pragma unroll
      for (int ni = 0; ni < 4; ++ni) {
        int nn = 64 * w + 16 * ni + (lane & 15);
        half8 bfr = *reinterpret_cast<const half8*>(Bc + nn * 128 + (jb ^ ((nn & 7) << 4)));
#pragma unroll
        for (int mi = 0; mi < 2; ++mi)
          acc[mi][ni] = __builtin_amdgcn_mfma_f32_16x16x32_f16(afr[mi], bfr, acc[mi][ni], 0, 0, 0);
      }
    }
  }
  // s1/s2: reduce over the 8 threads sharing a row (contiguous lanes)
  x1 += __shfl_xor(x1, 1); x1 += __shfl_xor(x1, 2); x1 += __shfl_xor(x1, 4);
  x2 += __shfl_xor(x2, 1); x2 += __shfl_xor(x2, 2); x2 += __shfl_xor(x2, 4);
  if (au == 0) { s1o[i0 + ar] = x1; s2o[i0 + ar] = x2; }
  // epilogue: pre-swizzled WhT store (unit8 XOR (c&7), within 64-n blocks)
  _Float16* whtb = WhT + (size_t)b * 256 * 2048;
#pragma unroll
  for (int mi = 0; mi < 2; ++mi)
#pragma unroll
    for (int ni = 0; ni < 4; ++ni) {
      int c = 64 * w + 16 * ni + (lane & 15);
      int nb = n0 + 16 * mi + (lane >> 4) * 4;
      int np = nb ^ ((c & 7) << 3);
      f32x4 a = acc[mi][ni];
      half4 hv = {(_Float16)a[0], (_Float16)a[1], (_Float16)a[2], (_Float16)a[3]};
      *reinterpret_cast<half4*>(whtb + (size_t)c * 2048 + np) = hv;
    }
}

// ---------------- K3: fused softmax(P) @ Wh + ELU, register-built P ----------------
// 512 blocks: bid&7 = batch (XCD affinity), 32 row-blocks x 2 col-groups
// wave: 16 rows x 128 cols (ni=8); B double-buffered in LDS, 1 barrier/tile
__global__ __launch_bounds__(256) void k_attn(const _Float16* __restrict__ WhT,
                                              const float* __restrict__ s1,
                                              const float* __restrict__ s2,
                                              const float* __restrict__ smax,
                                              float* __restrict__ out) {
  __shared__ _Float16 Bb[2][128 * 64];  // 16 KB each
  const int t = threadIdx.x, lane = t & 63, w = t >> 6;
  const int bid = blockIdx.x;
  const int b = bid & 7;
  const int r = bid >> 3;
  const int i0 = (r & 31) * 64;
  const int c0 = (r >> 5) * 128;
  const _Float16* whtb = WhT + ((size_t)b * 256 + c0) * 2048;
  const float* s2b = s2 + b * 2048;
  const int arow = lane & 15;
  const int grow = i0 + w * 16 + arow;
  float s1v = s1[b * 2048 + grow];
  float mrow = s1v + smax[b];
  mrow = fmaxf(mrow, ALPHA * mrow);  // closed-form row max (LeakyReLU monotonic)
  float dsum = 0.f;
  f32x4 acc[8];
#pragma unroll
  for (int ni = 0; ni < 8; ++ni) acc[ni] = (f32x4){0.f, 0.f, 0.f, 0.f};

  // prologue: stage tile 0
#pragma unroll
  for (int q = 0; q < 4; ++q) {
    int idx = (q * 4 + w) * 64 + lane;
    int cl = idx >> 3, uu = idx & 7;
    gload_lds16(whtb + (size_t)cl * 2048 + uu * 8, (char*)&Bb[0][0] + idx * 16);
  }

  for (int jt = 0; jt < 32; ++jt) {
    const int cur = jt & 1;
    __syncthreads();  // drains B(jt); separates buffer reuse
    if (jt < 31) {
      const int j0n = (jt + 1) * 64;
#pragma unroll
      for (int q = 0; q < 4; ++q) {
        int idx = (q * 4 + w) * 64 + lane;
        int cl = idx >> 3, uu = idx & 7;
        gload_lds16(whtb + (size_t)cl * 2048 + j0n + uu * 8, (char*)&Bb[cur ^ 1][0] + idx * 16);
      }
    }
    const int j0 = jt * 64;
    const char* Bc = (const char*)&Bb[cur][0];
#pragma unroll
    for (int kk = 0; kk < 2; ++kk) {
      const int jl = (lane >> 4) * 8 + kk * 32;
      float4 sA = *reinterpret_cast<const float4*>(s2b + j0 + jl);
      float4 sB = *reinterpret_cast<const float4*>(s2b + j0 + jl + 4);
      half8 afr;
      float e, p;
      e = s1v + sA.x; e = fmaxf(e, ALPHA * e); p = __expf(e - mrow); afr[0] = (_Float16)p; dsum += p;
      e = s1v + sA.y; e = fmaxf(e, ALPHA * e); p = __expf(e - mrow); afr[1] = (_Float16)p; dsum += p;
      e = s1v + sA.z; e = fmaxf(e, ALPHA * e); p = __expf(e - mrow); afr[2] = (_Float16)p; dsum += p;
      e = s1v + sA.w; e = fmaxf(e, ALPHA * e); p = __expf(e - mrow); afr[3] = (_Float16)p; dsum += p;
      e = s1v + sB.x; e = fmaxf(e, ALPHA * e); p = __expf(e - mrow); afr[4] = (_Float16)p; dsum += p;
      e = s1v + sB.y; e = fmaxf(e, ALPHA * e); p = __expf(e - mrow); afr[5] = (_Float16)p; dsum += p;
      e = s1v + sB.z; e = fmaxf(e, ALPHA * e); p = __expf(e - mrow); afr[6] = (_Float16)p; dsum += p;
      e = s1v + sB.w; e = fmaxf(e, ALPHA * e); p = __expf(e - mrow); afr[7] = (_Float16)p; dsum += p;
      const int jb = jl * 2;
#pragma unroll
      for (int ni = 0; ni < 8; ++ni) {
        int cl = 16 * ni + arow;
        half8 bfr = *reinterpret_cast<const half8*>(Bc + cl * 128 + (jb ^ ((cl & 7) << 4)));
        acc[ni] = __builtin_amdgcn_mfma_f32_16x16x32_f16(afr, bfr, acc[ni], 0, 0, 0);
      }
    }
  }
  // denominator: reduce over the 4 lanes sharing each A-row, then redistribute to C/D rows
  dsum += __shfl_xor(dsum, 16);
  dsum += __shfl_xor(dsum, 32);
  float inv[4];
#pragma unroll
  for (int reg = 0; reg < 4; ++reg) {
    float d = __shfl(dsum, (lane >> 4) * 4 + reg);
    inv[reg] = 1.f / d;
  }
  const size_t ob = ((size_t)b * 2048 + i0 + w * 16) * 256 + c0;
#pragma unroll
  for (int ni = 0; ni < 8; ++ni) {
    int c = 16 * ni + arow;
#pragma unroll
    for (int reg = 0; reg < 4; ++reg) {
      int rr = (lane >> 4) * 4 + reg;
      float v = acc[ni][reg] * inv[reg];
      v = v > 0.f ? v : (__expf(v) - 1.f);
      out[ob + (size_t)rr * 256 + c] = v;
    }
  }
}

extern "C" void kernel_launch(void* const* d_in, const int* in_sizes, int n_in,
                              void* d_out, int out_size, void* d_ws, size_t ws_size,
                              hipStream_t stream) {
  (void)in_sizes; (void)n_in; (void)out_size; (void)ws_size;
  const float* h = (const float*)d_in[0];
  const float* W = (const float*)d_in[1];
  const float* a1 = (const float*)d_in[2];
  const float* a2 = (const float*)d_in[3];
  float* out = (float*)d_out;
  char* ws = (char*)d_ws;
  _Float16* WhT = (_Float16*)(ws);             // 8*256*2048*2 = 8388608 B (pre-swizzled)
  _Float16* W16 = (_Float16*)(ws + 8388608);   // 262144 B (pre-swizzled)
  float* u1 = (float*)(ws + 8650752);
  float* u2 = (float*)(ws + 8652800);
  float* s1 = (float*)(ws + 8654848);          // 16384 floats
  float* s2 = (float*)(ws + 8720384);          // 16384 floats
  float* smax = (float*)(ws + 8785920);        // 8 floats

  hipLaunchKernelGGL(k_convW, dim3(128), dim3(256), 0, stream, W, W16);
  hipLaunchKernelGGL(k_uvec, dim3(512), dim3(256), 0, stream, W, a1, a2, u1, u2);
  hipLaunchKernelGGL(k_gemm_wh, dim3(512), dim3(256), 0, stream, h, W16, u1, u2, s1, s2, WhT);
  hipLaunchKernelGGL(k_smax, dim3(8), dim3(256), 0, stream, s2, smax);
  hipLaunchKernelGGL(k_attn, dim3(512), dim3(256), 0, stream, WhT, s1, s2, smax, out);
}